// Round 3
// baseline (2194.314 us; speedup 1.0000x reference)
//
#include <hip/hip_runtime.h>

// Problem constants: N=Na=10000, d_in=256, d_out=64, n_rel=3
#define NN    10000
#define NA    10000
#define DIN   256
#define DOUT  64
#define INV_T (1.0f / 0.07f)
#define CAPW  192    // split path: max hits/row; Binomial(10000,0.01) max ~150, +4 sigma
#define CAP   1024   // fused-fallback path
#define PROBE_PASSES 14  // R5: measurement probe -- see comment below

typedef unsigned int uv4 __attribute__((ext_vector_type(4)));

// adjs layout: int32-per-bool (A/B-verified R1/R2 in previous session).
//
// R5 MEASUREMENT PROBE (to be reverted): three structurally different kernels
// (fused / MLP-batched / split) all bench 1400 +- 25us, and R3's single-dispatch
// round proves dur_us contains >=626us of harness fills. Our kernel is below the
// top-5 cutoff every round, so its true cost ([~100, ~620]us) is invisible.
// This round adds 14 cache-defeating dummy scan passes (rotating relations,
// 400MB each, asm keep-alive vs DCE) to K1. That pushes scan_kernel above the
// 751us top-5 cutoff -> direct hbm_gbps/VALUBusy/Occupancy readout, and
// scan-per-pass = (dur_us - 1400)/14. Real scan/compact/attn logic untouched.

// ---- K1: streaming scan of adj rows -> compact [cnt, list] in d_ws ----
__global__ __launch_bounds__(256) void scan_kernel(
    const unsigned int* __restrict__ adjs,  // [n_rel, NA, NN] int32 bools
    const int*          __restrict__ idxp,  // [1]
    int*                __restrict__ wcnt,  // [NA]
    int*                __restrict__ wlist) // [NA, CAPW]
{
    __shared__ int jl[CAPW];
    __shared__ int cnt;

    const int t   = threadIdx.x;
    const int row = blockIdx.x;
    if (t == 0) cnt = 0;
    __syncthreads();

    const int idx = idxp[0];
    const uv4* ar = (const uv4*)(adjs + ((size_t)idx * NA + row) * NN);

    // real scan: issue ALL loads first (10 outstanding 16B loads/thread)
    uv4 v[10];
#pragma unroll
    for (int it = 0; it < 10; ++it) {
        const int cch = t + 256 * it;
        uv4 vv = {0u, 0u, 0u, 0u};
        if (cch < NN / 4) vv = ar[cch];
        v[it] = vv;
    }
    unsigned long long hm = 0ull;
#pragma unroll
    for (int it = 0; it < 10; ++it) {
        unsigned int nz = (v[it].x ? 1u : 0u) | (v[it].y ? 2u : 0u) |
                          (v[it].z ? 4u : 0u) | (v[it].w ? 8u : 0u);
        hm |= (unsigned long long)nz << (it * 4);
    }
    const int mycnt = __popcll(hm);
    int base = 0;
    if (mycnt) base = atomicAdd(&cnt, mycnt);
    while (hm) {
        const int b = __ffsll((long long)hm) - 1;
        hm &= hm - 1;
        const int it = b >> 2, ww = b & 3;
        if (base < CAPW) jl[base] = (t + 256 * it) * 4 + ww;
        ++base;
    }

    // ---- PROBE: 14 dummy passes, same access pattern, rotating relations ----
    // (idx+p)%3 spaces successive 400MB passes across the 1.2GB buffer; with
    // L3=256MB every pass is a cold HBM stream. Results kept alive via asm.
    {
        unsigned int dummy = 0;
        for (int p = 1; p <= PROBE_PASSES; ++p) {
            int rel = idx + p; while (rel >= 3) rel -= 3;
            const uv4* dr = (const uv4*)(adjs + ((size_t)rel * NA + row) * NN);
            uv4 dv[10];
#pragma unroll
            for (int it = 0; it < 10; ++it) {
                const int cch = t + 256 * it;
                uv4 vv = {0u, 0u, 0u, 0u};
                if (cch < NN / 4) vv = dr[cch];
                dv[it] = vv;
            }
#pragma unroll
            for (int it = 0; it < 10; ++it)
                dummy |= dv[it].x | dv[it].y | dv[it].z | dv[it].w;
        }
        asm volatile("" :: "v"(dummy));   // keep probe loads live (rule #17)
    }

    __syncthreads();

    int nc = cnt; if (nc > CAPW) nc = CAPW;
    if (t == 0) wcnt[row] = nc;
    for (int s = t; s < nc; s += 256) wlist[(size_t)row * CAPW + s] = jl[s];
}

// ---- K2: proj + sparse masked-softmax attention from compact lists ----
__global__ __launch_bounds__(256) void attn2_kernel(
    const float* __restrict__ x,       // [NN, DOUT]
    const float* __restrict__ weight,  // [n_rel]
    const int*   __restrict__ idxp,    // [1]
    const float* __restrict__ anchor,  // [NA, DIN]
    const float* __restrict__ wt,      // [DIN, DOUT]
    const int*   __restrict__ wcnt,    // [NA]
    const int*   __restrict__ wlist,   // [NA, CAPW]
    float* __restrict__ out)           // [NA, DOUT]
{
    __shared__ float arow[DIN];
    __shared__ float pr[DOUT];
    __shared__ int   jl[CAPW];
    __shared__ float ps[CAPW];
    __shared__ float red[256];
    __shared__ float wred[8];

    const int t    = threadIdx.x;
    const int row  = blockIdx.x;
    const int w    = t >> 6;
    const int lane = t & 63;

    if (t < 64) ((float4*)arow)[t] =
        ((const float4*)(anchor + (size_t)row * DIN))[t];
    __syncthreads();   // arow ready

    const int idx = idxp[0];
    const int nc  = wcnt[row];   // uniform scalar load
    for (int s = t; s < nc; s += 256) jl[s] = wlist[(size_t)row * CAPW + s];

    // ---- Phase P: proj[row] = anchor[row] @ wt ----
    {
        const int seg = t >> 6, c = t & 63;
        float acc = 0.f;
        const int k0 = seg * 64;
#pragma unroll 8
        for (int k = k0; k < k0 + 64; ++k)
            acc = fmaf(arow[k], wt[k * DOUT + c], acc);  // wt coalesced across c
        red[t] = acc;
    }
    __syncthreads();   // finalizes red and jl

    if (t < DOUT) pr[t] = red[t] + red[64 + t] + red[128 + t] + red[192 + t];
    __syncthreads();

    if (nc == 0) {
        if (t < DOUT) out[(size_t)row * DOUT + t] = 0.f;
        return;
    }

    // ---- Phase B: scores; 16 lanes cooperate per score ----
    {
        const int g = t >> 4, l = t & 15;
        const float4 pv = ((const float4*)pr)[l];
        for (int s = g; s < nc; s += 16) {
            const int j = jl[s];
            float4 xv = ((const float4*)(x + (size_t)j * DOUT))[l];
            float d = xv.x * pv.x + xv.y * pv.y + xv.z * pv.z + xv.w * pv.w;
            d += __shfl_xor(d, 1);
            d += __shfl_xor(d, 2);
            d += __shfl_xor(d, 4);
            d += __shfl_xor(d, 8);
            if (l == 0) ps[s] = d * INV_T;
        }
    }
    __syncthreads();

    // ---- Phase C: softmax ----
    float lm = -3.4e38f;
    for (int s = t; s < nc; s += 256) lm = fmaxf(lm, ps[s]);
#pragma unroll
    for (int o = 32; o > 0; o >>= 1) lm = fmaxf(lm, __shfl_xor(lm, o));
    if (lane == 0) wred[w] = lm;
    __syncthreads();
    const float m = fmaxf(fmaxf(wred[0], wred[1]), fmaxf(wred[2], wred[3]));

    float lsum = 0.f;
    for (int s = t; s < nc; s += 256) {
        float p = __expf(ps[s] - m);
        ps[s] = p;
        lsum += p;
    }
#pragma unroll
    for (int o = 32; o > 0; o >>= 1) lsum += __shfl_xor(lsum, o);
    if (lane == 0) wred[4 + w] = lsum;
    __syncthreads();   // finalizes ps[]
    const float scale = weight[idx] /
        (wred[4] + wred[5] + wred[6] + wred[7]);

    // ---- Phase D: out[row,:] = scale * sum_s ps[s] * x[jl[s],:] ----
    {
        const int c = t & 63, seg = t >> 6;
        float acc = 0.f;
        for (int s = seg; s < nc; s += 4)
            acc = fmaf(ps[s], x[(size_t)jl[s] * DOUT + c], acc);
        red[t] = acc;
        __syncthreads();
        if (t < DOUT) {
            float o = (red[t] + red[64 + t] + red[128 + t] + red[192 + t]) * scale;
            __builtin_nontemporal_store(o, out + (size_t)row * DOUT + t);
        }
    }
}

// ---- Fused fallback (R3 kernel), used only if ws_size is too small ----
__global__ __launch_bounds__(256) void attn_kernel(
    const float* __restrict__ x,
    const float* __restrict__ weight,
    const unsigned int* __restrict__ adjs,
    const int*   __restrict__ idxp,
    const float* __restrict__ anchor,
    const float* __restrict__ wt,
    float* __restrict__ out)
{
    __shared__ float arow[DIN];
    __shared__ float pr[DOUT];
    __shared__ int   jl[CAP];
    __shared__ float ps[CAP];
    __shared__ float red[256];
    __shared__ float wred[8];
    __shared__ int   cnt;

    const int t    = threadIdx.x;
    const int row  = blockIdx.x;
    const int w    = t >> 6;
    const int lane = t & 63;

    if (t < 64) ((float4*)arow)[t] =
        ((const float4*)(anchor + (size_t)row * DIN))[t];
    if (t == 0) cnt = 0;
    __syncthreads();

    const int idx = idxp[0];

    {
        const uv4* ar = (const uv4*)(adjs + ((size_t)idx * NA + row) * NN);
        uv4 v[10];
#pragma unroll
        for (int it = 0; it < 10; ++it) {
            const int cch = t + 256 * it;
            uv4 vv = {0u, 0u, 0u, 0u};
            if (cch < NN / 4) vv = __builtin_nontemporal_load(ar + cch);
            v[it] = vv;
        }
        unsigned long long hm = 0ull;
#pragma unroll
        for (int it = 0; it < 10; ++it) {
            unsigned int nz = (v[it].x ? 1u : 0u) | (v[it].y ? 2u : 0u) |
                              (v[it].z ? 4u : 0u) | (v[it].w ? 8u : 0u);
            hm |= (unsigned long long)nz << (it * 4);
        }
        const int mycnt = __popcll(hm);
        int base = 0;
        if (mycnt) base = atomicAdd(&cnt, mycnt);
        while (hm) {
            const int b = __ffsll((long long)hm) - 1;
            hm &= hm - 1;
            const int it = b >> 2, ww = b & 3;
            if (base < CAP) jl[base] = (t + 256 * it) * 4 + ww;
            ++base;
        }
    }

    {
        const int seg = t >> 6, c = t & 63;
        float acc = 0.f;
        const int k0 = seg * 64;
#pragma unroll 8
        for (int k = k0; k < k0 + 64; ++k)
            acc = fmaf(arow[k], wt[k * DOUT + c], acc);
        red[t] = acc;
    }
    __syncthreads();

    if (t < DOUT) pr[t] = red[t] + red[64 + t] + red[128 + t] + red[192 + t];
    int nc = cnt; if (nc > CAP) nc = CAP;
    __syncthreads();

    if (nc == 0) {
        if (t < DOUT) out[(size_t)row * DOUT + t] = 0.f;
        return;
    }

    {
        const int g = t >> 4, l = t & 15;
        const float4 pv = ((const float4*)pr)[l];
        for (int s = g; s < nc; s += 16) {
            const int j = jl[s];
            float4 xv = ((const float4*)(x + (size_t)j * DOUT))[l];
            float d = xv.x * pv.x + xv.y * pv.y + xv.z * pv.z + xv.w * pv.w;
            d += __shfl_xor(d, 1);
            d += __shfl_xor(d, 2);
            d += __shfl_xor(d, 4);
            d += __shfl_xor(d, 8);
            if (l == 0) ps[s] = d * INV_T;
        }
    }
    __syncthreads();

    float lm = -3.4e38f;
    for (int s = t; s < nc; s += 256) lm = fmaxf(lm, ps[s]);
#pragma unroll
    for (int o = 32; o > 0; o >>= 1) lm = fmaxf(lm, __shfl_xor(lm, o));
    if (lane == 0) wred[w] = lm;
    __syncthreads();
    const float m = fmaxf(fmaxf(wred[0], wred[1]), fmaxf(wred[2], wred[3]));

    float lsum = 0.f;
    for (int s = t; s < nc; s += 256) {
        float p = __expf(ps[s] - m);
        ps[s] = p;
        lsum += p;
    }
#pragma unroll
    for (int o = 32; o > 0; o >>= 1) lsum += __shfl_xor(lsum, o);
    if (lane == 0) wred[4 + w] = lsum;
    __syncthreads();
    const float scale = weight[idx] /
        (wred[4] + wred[5] + wred[6] + wred[7]);

    {
        const int c = t & 63, seg = t >> 6;
        float acc = 0.f;
        for (int s = seg; s < nc; s += 4)
            acc = fmaf(ps[s], x[(size_t)jl[s] * DOUT + c], acc);
        red[t] = acc;
        __syncthreads();
        if (t < DOUT) {
            float o = (red[t] + red[64 + t] + red[128 + t] + red[192 + t]) * scale;
            __builtin_nontemporal_store(o, out + (size_t)row * DOUT + t);
        }
    }
}

extern "C" void kernel_launch(void* const* d_in, const int* in_sizes, int n_in,
                              void* d_out, int out_size, void* d_ws, size_t ws_size,
                              hipStream_t stream) {
    const float*        x      = (const float*)d_in[0];
    const float*        weight = (const float*)d_in[1];
    const unsigned int* adjs   = (const unsigned int*)d_in[2];
    const int*          idxp   = (const int*)d_in[3];
    const float*        anchor = (const float*)d_in[4];
    const float*        wt     = (const float*)d_in[5];
    float*              out    = (float*)d_out;

    const size_t need = sizeof(int) * ((size_t)NA + (size_t)NA * CAPW);
    if (d_ws && ws_size >= need) {
        int* wcnt  = (int*)d_ws;
        int* wlist = wcnt + NA;
        scan_kernel<<<NA, 256, 0, stream>>>(adjs, idxp, wcnt, wlist);
        attn2_kernel<<<NA, 256, 0, stream>>>(x, weight, idxp, anchor, wt,
                                             wcnt, wlist, out);
    } else {
        attn_kernel<<<NA, 256, 0, stream>>>(x, weight, adjs, idxp, anchor, wt, out);
    }
}

// Round 4
// 1874.184 us; speedup vs baseline: 1.1708x; 1.1708x over previous
//
#include <hip/hip_runtime.h>

// Problem constants: N=Na=10000, d_in=256, d_out=64, n_rel=3
#define NN    10000
#define NA    10000
#define DIN   256
#define DOUT  64
#define INV_T (1.0f / 0.07f)
#define CAPW  192    // split path: max hits/row; Binomial(10000,0.01) max ~150, +4 sigma
#define CAP   1024   // fused-fallback path
#define ATTN2_REPEATS 8  // R6 probe: attn2 cost = (dur_R6 - dur_R4)/7

typedef unsigned int uv4 __attribute__((ext_vector_type(4)));

// adjs layout: int32-per-bool (A/B-verified R1/R2 in previous session).
//
// SESSION LEDGER
//  R3 fused MLP-batch:      1377us. R4 split scan+attn2: 1417us (same band).
//  R5 scan x15 probe:       2194us -> scan = ~59us/pass steady-state, ~60-105us
//     single-pass (at its ~63us BW floor; logical 6.7 TB/s, L3 absorbs half).
//     VALUBusy 7%, occ 77% -> compaction is free. SCAN IS DONE.
//  Arithmetic: fill ~755us every iter; M (misc harness) + attn2 = 556us,
//     attn2 invisible (below top-5 cutoff). R6 measures attn2 directly.
//  R6 MEASUREMENT PROBE (this file): launch attn2 8x (idempotent relaunch --
//     reads unchanged ws/lists, overwrites same out). attn2 = delta/7.

// ---- K1: pure-streaming scan of adj rows -> compact [cnt, list] in d_ws ----
__global__ __launch_bounds__(256) void scan_kernel(
    const unsigned int* __restrict__ adjs,  // [n_rel, NA, NN] int32 bools
    const int*          __restrict__ idxp,  // [1]
    int*                __restrict__ wcnt,  // [NA]
    int*                __restrict__ wlist) // [NA, CAPW]
{
    __shared__ int jl[CAPW];
    __shared__ int cnt;

    const int t   = threadIdx.x;
    const int row = blockIdx.x;
    if (t == 0) cnt = 0;
    __syncthreads();

    const int idx = idxp[0];
    const uv4* ar = (const uv4*)(adjs + ((size_t)idx * NA + row) * NN);

    uv4 v[10];
#pragma unroll
    for (int it = 0; it < 10; ++it) {
        const int cch = t + 256 * it;
        uv4 vv = {0u, 0u, 0u, 0u};
        if (cch < NN / 4) vv = ar[cch];
        v[it] = vv;
    }
    unsigned long long hm = 0ull;
#pragma unroll
    for (int it = 0; it < 10; ++it) {
        unsigned int nz = (v[it].x ? 1u : 0u) | (v[it].y ? 2u : 0u) |
                          (v[it].z ? 4u : 0u) | (v[it].w ? 8u : 0u);
        hm |= (unsigned long long)nz << (it * 4);
    }
    const int mycnt = __popcll(hm);
    int base = 0;
    if (mycnt) base = atomicAdd(&cnt, mycnt);
    while (hm) {
        const int b = __ffsll((long long)hm) - 1;
        hm &= hm - 1;
        const int it = b >> 2, ww = b & 3;
        if (base < CAPW) jl[base] = (t + 256 * it) * 4 + ww;
        ++base;
    }
    __syncthreads();

    int nc = cnt; if (nc > CAPW) nc = CAPW;
    if (t == 0) wcnt[row] = nc;
    for (int s = t; s < nc; s += 256) wlist[(size_t)row * CAPW + s] = jl[s];
}

// ---- K2: proj + sparse masked-softmax attention from compact lists ----
__global__ __launch_bounds__(256) void attn2_kernel(
    const float* __restrict__ x,       // [NN, DOUT]
    const float* __restrict__ weight,  // [n_rel]
    const int*   __restrict__ idxp,    // [1]
    const float* __restrict__ anchor,  // [NA, DIN]
    const float* __restrict__ wt,      // [DIN, DOUT]
    const int*   __restrict__ wcnt,    // [NA]
    const int*   __restrict__ wlist,   // [NA, CAPW]
    float* __restrict__ out)           // [NA, DOUT]
{
    __shared__ float arow[DIN];
    __shared__ float pr[DOUT];
    __shared__ int   jl[CAPW];
    __shared__ float ps[CAPW];
    __shared__ float red[256];
    __shared__ float wred[8];

    const int t    = threadIdx.x;
    const int row  = blockIdx.x;
    const int w    = t >> 6;
    const int lane = t & 63;

    if (t < 64) ((float4*)arow)[t] =
        ((const float4*)(anchor + (size_t)row * DIN))[t];
    __syncthreads();   // arow ready

    const int idx = idxp[0];
    const int nc  = wcnt[row];   // uniform scalar load
    for (int s = t; s < nc; s += 256) jl[s] = wlist[(size_t)row * CAPW + s];

    // ---- Phase P: proj[row] = anchor[row] @ wt ----
    {
        const int seg = t >> 6, c = t & 63;
        float acc = 0.f;
        const int k0 = seg * 64;
#pragma unroll 8
        for (int k = k0; k < k0 + 64; ++k)
            acc = fmaf(arow[k], wt[k * DOUT + c], acc);  // wt coalesced across c
        red[t] = acc;
    }
    __syncthreads();   // finalizes red and jl

    if (t < DOUT) pr[t] = red[t] + red[64 + t] + red[128 + t] + red[192 + t];
    __syncthreads();

    if (nc == 0) {
        if (t < DOUT) out[(size_t)row * DOUT + t] = 0.f;
        return;
    }

    // ---- Phase B: scores; 16 lanes cooperate per score ----
    {
        const int g = t >> 4, l = t & 15;
        const float4 pv = ((const float4*)pr)[l];
        for (int s = g; s < nc; s += 16) {
            const int j = jl[s];
            float4 xv = ((const float4*)(x + (size_t)j * DOUT))[l];
            float d = xv.x * pv.x + xv.y * pv.y + xv.z * pv.z + xv.w * pv.w;
            d += __shfl_xor(d, 1);
            d += __shfl_xor(d, 2);
            d += __shfl_xor(d, 4);
            d += __shfl_xor(d, 8);
            if (l == 0) ps[s] = d * INV_T;
        }
    }
    __syncthreads();

    // ---- Phase C: softmax ----
    float lm = -3.4e38f;
    for (int s = t; s < nc; s += 256) lm = fmaxf(lm, ps[s]);
#pragma unroll
    for (int o = 32; o > 0; o >>= 1) lm = fmaxf(lm, __shfl_xor(lm, o));
    if (lane == 0) wred[w] = lm;
    __syncthreads();
    const float m = fmaxf(fmaxf(wred[0], wred[1]), fmaxf(wred[2], wred[3]));

    float lsum = 0.f;
    for (int s = t; s < nc; s += 256) {
        float p = __expf(ps[s] - m);
        ps[s] = p;
        lsum += p;
    }
#pragma unroll
    for (int o = 32; o > 0; o >>= 1) lsum += __shfl_xor(lsum, o);
    if (lane == 0) wred[4 + w] = lsum;
    __syncthreads();   // finalizes ps[]
    const float scale = weight[idx] /
        (wred[4] + wred[5] + wred[6] + wred[7]);

    // ---- Phase D: out[row,:] = scale * sum_s ps[s] * x[jl[s],:] ----
    {
        const int c = t & 63, seg = t >> 6;
        float acc = 0.f;
        for (int s = seg; s < nc; s += 4)
            acc = fmaf(ps[s], x[(size_t)jl[s] * DOUT + c], acc);
        red[t] = acc;
        __syncthreads();
        if (t < DOUT) {
            float o = (red[t] + red[64 + t] + red[128 + t] + red[192 + t]) * scale;
            __builtin_nontemporal_store(o, out + (size_t)row * DOUT + t);
        }
    }
}

// ---- Fused fallback (R3 kernel), used only if ws_size is too small ----
__global__ __launch_bounds__(256) void attn_kernel(
    const float* __restrict__ x,
    const float* __restrict__ weight,
    const unsigned int* __restrict__ adjs,
    const int*   __restrict__ idxp,
    const float* __restrict__ anchor,
    const float* __restrict__ wt,
    float* __restrict__ out)
{
    __shared__ float arow[DIN];
    __shared__ float pr[DOUT];
    __shared__ int   jl[CAP];
    __shared__ float ps[CAP];
    __shared__ float red[256];
    __shared__ float wred[8];
    __shared__ int   cnt;

    const int t    = threadIdx.x;
    const int row  = blockIdx.x;
    const int w    = t >> 6;
    const int lane = t & 63;

    if (t < 64) ((float4*)arow)[t] =
        ((const float4*)(anchor + (size_t)row * DIN))[t];
    if (t == 0) cnt = 0;
    __syncthreads();

    const int idx = idxp[0];

    {
        const uv4* ar = (const uv4*)(adjs + ((size_t)idx * NA + row) * NN);
        uv4 v[10];
#pragma unroll
        for (int it = 0; it < 10; ++it) {
            const int cch = t + 256 * it;
            uv4 vv = {0u, 0u, 0u, 0u};
            if (cch < NN / 4) vv = __builtin_nontemporal_load(ar + cch);
            v[it] = vv;
        }
        unsigned long long hm = 0ull;
#pragma unroll
        for (int it = 0; it < 10; ++it) {
            unsigned int nz = (v[it].x ? 1u : 0u) | (v[it].y ? 2u : 0u) |
                              (v[it].z ? 4u : 0u) | (v[it].w ? 8u : 0u);
            hm |= (unsigned long long)nz << (it * 4);
        }
        const int mycnt = __popcll(hm);
        int base = 0;
        if (mycnt) base = atomicAdd(&cnt, mycnt);
        while (hm) {
            const int b = __ffsll((long long)hm) - 1;
            hm &= hm - 1;
            const int it = b >> 2, ww = b & 3;
            if (base < CAP) jl[base] = (t + 256 * it) * 4 + ww;
            ++base;
        }
    }

    {
        const int seg = t >> 6, c = t & 63;
        float acc = 0.f;
        const int k0 = seg * 64;
#pragma unroll 8
        for (int k = k0; k < k0 + 64; ++k)
            acc = fmaf(arow[k], wt[k * DOUT + c], acc);
        red[t] = acc;
    }
    __syncthreads();

    if (t < DOUT) pr[t] = red[t] + red[64 + t] + red[128 + t] + red[192 + t];
    int nc = cnt; if (nc > CAP) nc = CAP;
    __syncthreads();

    if (nc == 0) {
        if (t < DOUT) out[(size_t)row * DOUT + t] = 0.f;
        return;
    }

    {
        const int g = t >> 4, l = t & 15;
        const float4 pv = ((const float4*)pr)[l];
        for (int s = g; s < nc; s += 16) {
            const int j = jl[s];
            float4 xv = ((const float4*)(x + (size_t)j * DOUT))[l];
            float d = xv.x * pv.x + xv.y * pv.y + xv.z * pv.z + xv.w * pv.w;
            d += __shfl_xor(d, 1);
            d += __shfl_xor(d, 2);
            d += __shfl_xor(d, 4);
            d += __shfl_xor(d, 8);
            if (l == 0) ps[s] = d * INV_T;
        }
    }
    __syncthreads();

    float lm = -3.4e38f;
    for (int s = t; s < nc; s += 256) lm = fmaxf(lm, ps[s]);
#pragma unroll
    for (int o = 32; o > 0; o >>= 1) lm = fmaxf(lm, __shfl_xor(lm, o));
    if (lane == 0) wred[w] = lm;
    __syncthreads();
    const float m = fmaxf(fmaxf(wred[0], wred[1]), fmaxf(wred[2], wred[3]));

    float lsum = 0.f;
    for (int s = t; s < nc; s += 256) {
        float p = __expf(ps[s] - m);
        ps[s] = p;
        lsum += p;
    }
#pragma unroll
    for (int o = 32; o > 0; o >>= 1) lsum += __shfl_xor(lsum, o);
    if (lane == 0) wred[4 + w] = lsum;
    __syncthreads();
    const float scale = weight[idx] /
        (wred[4] + wred[5] + wred[6] + wred[7]);

    {
        const int c = t & 63, seg = t >> 6;
        float acc = 0.f;
        for (int s = seg; s < nc; s += 4)
            acc = fmaf(ps[s], x[(size_t)jl[s] * DOUT + c], acc);
        red[t] = acc;
        __syncthreads();
        if (t < DOUT) {
            float o = (red[t] + red[64 + t] + red[128 + t] + red[192 + t]) * scale;
            __builtin_nontemporal_store(o, out + (size_t)row * DOUT + t);
        }
    }
}

extern "C" void kernel_launch(void* const* d_in, const int* in_sizes, int n_in,
                              void* d_out, int out_size, void* d_ws, size_t ws_size,
                              hipStream_t stream) {
    const float*        x      = (const float*)d_in[0];
    const float*        weight = (const float*)d_in[1];
    const unsigned int* adjs   = (const unsigned int*)d_in[2];
    const int*          idxp   = (const int*)d_in[3];
    const float*        anchor = (const float*)d_in[4];
    const float*        wt     = (const float*)d_in[5];
    float*              out    = (float*)d_out;

    const size_t need = sizeof(int) * ((size_t)NA + (size_t)NA * CAPW);
    if (d_ws && ws_size >= need) {
        int* wcnt  = (int*)d_ws;
        int* wlist = wcnt + NA;
        scan_kernel<<<NA, 256, 0, stream>>>(adjs, idxp, wcnt, wlist);
        // R6 probe: idempotent relaunch x8; attn2 cost = (dur - 1417)/7.
        for (int r = 0; r < ATTN2_REPEATS; ++r)
            attn2_kernel<<<NA, 256, 0, stream>>>(x, weight, idxp, anchor, wt,
                                                 wcnt, wlist, out);
    } else {
        attn_kernel<<<NA, 256, 0, stream>>>(x, weight, adjs, idxp, anchor, wt, out);
    }
}

// Round 6
// 1376.049 us; speedup vs baseline: 1.5946x; 1.3620x over previous
//
#include <hip/hip_runtime.h>

// Problem constants: N=Na=10000, d_in=256, d_out=64, n_rel=3
#define NN    10000
#define NA    10000
#define DIN   256
#define DOUT  64
#define INV_T (1.0f / 0.07f)
#define CAP   1024   // max adjacency-true entries per row; Binomial(10000,0.01) max ~150

typedef unsigned int uv4 __attribute__((ext_vector_type(4)));

// adjs layout: int32-per-bool (A/B-verified R1/R2 in previous session).
//
// SESSION LEDGER (final)
//  R3 fused MLP-batch: 1377us (best). R4 split scan+attn2: 1417us.
//  R5 scan x15 probe:  scan = ~66us single-pass == its 400MB/6.3TB/s BW floor
//     (logical 6.7 TB/s, VALUBusy 7%, occ 77% -> compaction free).
//  R6 attn2 x8 probe:  attn2 = ~65us/launch (latency-bound; ~20MB HBM traffic).
//  Window accounting:  fill ~755us (harness, 79% HBM peak) + restores ~530us
//     (harness) + ours ~91us fused (scan 66 + compute 65, ~40us overlapped via
//     8 blocks/CU inter-block concurrency). Controllable headroom ~25us = noise.
//  R7: infra failure (container died twice; kernel never ran). This file is
//     code-identical to the R3/R1-benched kernel (1377.5us, absmax 2.44e-4) --
//     resubmitted unchanged for the clean final measurement.

// ---- Fused kernel: scan+compact, proj, scores, softmax, output. 1 block/row. ----
__global__ __launch_bounds__(256) void attn_kernel(
    const float* __restrict__ x,        // [NN, DOUT]
    const float* __restrict__ weight,   // [n_rel]
    const unsigned int* __restrict__ adjs, // [n_rel, NA, NN] int32 bools
    const int*   __restrict__ idxp,     // [1]
    const float* __restrict__ anchor,   // [NA, DIN]
    const float* __restrict__ wt,       // [DIN, DOUT]
    float* __restrict__ out)            // [NA, DOUT]
{
    __shared__ float arow[DIN];   // anchor row
    __shared__ float pr[DOUT];    // projected row
    __shared__ int   jl[CAP];
    __shared__ float ps[CAP];
    __shared__ float red[256];
    __shared__ float wred[8];     // per-wave softmax partials (max: 0..3, sum: 4..7)
    __shared__ int   cnt;

    const int t    = threadIdx.x;
    const int row  = blockIdx.x;
    const int w    = t >> 6;      // wave id
    const int lane = t & 63;

    // stage anchor row (256 floats = 64 float4) + zero the compaction counter
    if (t < 64) ((float4*)arow)[t] =
        ((const float4*)(anchor + (size_t)row * DIN))[t];
    if (t == 0) cnt = 0;
    __syncthreads();

    const int idx = idxp[0];

    // ---- Phase A: NT scan of adj row (2500 uint4 = 10000 int32), compact ----
    // Issue ALL 10 16B NT loads before any test (max MLP), reduce to a 40-bit
    // nonzero mask (values dead after), one batched LDS atomicAdd per thread.
    {
        const uv4* ar = (const uv4*)(adjs + ((size_t)idx * NA + row) * NN);
        uv4 v[10];
#pragma unroll
        for (int it = 0; it < 10; ++it) {
            const int cch = t + 256 * it;
            uv4 vv = {0u, 0u, 0u, 0u};
            if (cch < NN / 4) vv = __builtin_nontemporal_load(ar + cch);
            v[it] = vv;
        }
        unsigned long long hm = 0ull;
#pragma unroll
        for (int it = 0; it < 10; ++it) {
            unsigned int nz = (v[it].x ? 1u : 0u) | (v[it].y ? 2u : 0u) |
                              (v[it].z ? 4u : 0u) | (v[it].w ? 8u : 0u);
            hm |= (unsigned long long)nz << (it * 4);
        }
        const int mycnt = __popcll(hm);
        int base = 0;
        if (mycnt) base = atomicAdd(&cnt, mycnt);
        while (hm) {
            const int b = __ffsll((long long)hm) - 1;   // word index 0..39
            hm &= hm - 1;
            const int it = b >> 2, ww = b & 3;
            if (base < CAP) jl[base] = (t + 256 * it) * 4 + ww;
            ++base;
        }
    }

    // ---- Phase P (same barrier interval): proj[row] = anchor[row] @ wt ----
    {
        const int seg = t >> 6, c = t & 63;
        float acc = 0.f;
        const int k0 = seg * 64;
#pragma unroll 8
        for (int k = k0; k < k0 + 64; ++k)
            acc = fmaf(arow[k], wt[k * DOUT + c], acc);  // wt coalesced across c
        red[t] = acc;
    }
    __syncthreads();   // finalizes cnt, jl, and proj partials

    if (t < DOUT) pr[t] = red[t] + red[64 + t] + red[128 + t] + red[192 + t];
    int nc = cnt; if (nc > CAP) nc = CAP;
    __syncthreads();

    if (nc == 0) {  // cannot occur at 1% density with this seed; stay defined
        if (t < DOUT) out[(size_t)row * DOUT + t] = 0.f;
        return;
    }

    // ---- Phase B: scores; 16 lanes cooperate per score (float4 per lane) ----
    {
        const int g = t >> 4, l = t & 15;
        const float4 pv = ((const float4*)pr)[l];
        for (int s = g; s < nc; s += 16) {
            const int j = jl[s];
            float4 xv = ((const float4*)(x + (size_t)j * DOUT))[l];
            float d = xv.x * pv.x + xv.y * pv.y + xv.z * pv.z + xv.w * pv.w;
            d += __shfl_xor(d, 1);
            d += __shfl_xor(d, 2);
            d += __shfl_xor(d, 4);
            d += __shfl_xor(d, 8);
            if (l == 0) ps[s] = d * INV_T;
        }
    }
    __syncthreads();

    // ---- Phase C: softmax (wave-shuffle reductions, 2 barriers total) ----
    float lm = -3.4e38f;
    for (int s = t; s < nc; s += 256) lm = fmaxf(lm, ps[s]);
#pragma unroll
    for (int o = 32; o > 0; o >>= 1) lm = fmaxf(lm, __shfl_xor(lm, o));
    if (lane == 0) wred[w] = lm;
    __syncthreads();
    const float m = fmaxf(fmaxf(wred[0], wred[1]), fmaxf(wred[2], wred[3]));

    float lsum = 0.f;
    for (int s = t; s < nc; s += 256) {
        float p = __expf(ps[s] - m);
        ps[s] = p;
        lsum += p;
    }
#pragma unroll
    for (int o = 32; o > 0; o >>= 1) lsum += __shfl_xor(lsum, o);
    if (lane == 0) wred[4 + w] = lsum;
    __syncthreads();   // also finalizes ps[] for Phase D
    const float scale = weight[idx] /
        (wred[4] + wred[5] + wred[6] + wred[7]);

    // ---- Phase D: out[row,:] = scale * sum_s ps[s] * x[jl[s],:] ----
    {
        const int c = t & 63, seg = t >> 6;
        float acc = 0.f;
        for (int s = seg; s < nc; s += 4)
            acc = fmaf(ps[s], x[(size_t)jl[s] * DOUT + c], acc);
        red[t] = acc;
        __syncthreads();
        if (t < DOUT) {
            float o = (red[t] + red[64 + t] + red[128 + t] + red[192 + t]) * scale;
            __builtin_nontemporal_store(o, out + (size_t)row * DOUT + t);
        }
    }
}

extern "C" void kernel_launch(void* const* d_in, const int* in_sizes, int n_in,
                              void* d_out, int out_size, void* d_ws, size_t ws_size,
                              hipStream_t stream) {
    const float*        x      = (const float*)d_in[0];
    const float*        weight = (const float*)d_in[1];
    const unsigned int* adjs   = (const unsigned int*)d_in[2];
    const int*          idxp   = (const int*)d_in[3];
    const float*        anchor = (const float*)d_in[4];
    const float*        wt     = (const float*)d_in[5];
    float*              out    = (float*)d_out;

    attn_kernel<<<NA, 256, 0, stream>>>(x, weight, adjs, idxp, anchor, wt, out);
}